// Round 4
// baseline (410.432 us; speedup 1.0000x reference)
//
#include <hip/hip_runtime.h>
#include <hip/hip_bf16.h>
#include <math.h>

// Problem constants
#define BB 16
#define NN 1024
#define EE 1024
#define HH 16
#define DD 64
#define THREE_E 3072
#define M_TOTAL (BB * NN)   // 16384

typedef __attribute__((ext_vector_type(8))) short bf16x8;   // 8 bf16 = 4 VGPR
typedef __attribute__((ext_vector_type(4))) short bf16x4;   // 4 bf16 = 2 VGPR
typedef __attribute__((ext_vector_type(4))) float floatx4;  // MFMA C/D

// Q pre-scale: 1/sqrt(64) * log2(e)  (scores land in exp2 domain)
#define SCALE_Q 0.18033688011112042f

static __device__ __forceinline__ unsigned short f2bf(float f) {
    union { float f; unsigned u; } x; x.f = f;
    unsigned r = x.u + 0x7fffu + ((x.u >> 16) & 1u);
    return (unsigned short)(r >> 16);
}

// raw v_exp_f32 — scores are bounded, skip OCML denormal guards
static __device__ __forceinline__ float fast_exp2(float x) {
#if __has_builtin(__builtin_amdgcn_exp2f)
    return __builtin_amdgcn_exp2f(x);
#else
    float r; __asm__("v_exp_f32 %0, %1" : "=v"(r) : "v"(x)); return r;
#endif
}

// pack 2x floatx4 -> bf16x8 via v_cvt_pk_bf16_f32 (RNE)
static __device__ __forceinline__ bf16x8 pack8v(floatx4 a, floatx4 b) {
    union { bf16x8 v; unsigned u[4]; } r;
    __hip_bfloat162 t;
    t = __float22bfloat162_rn(make_float2(a[0], a[1])); r.u[0] = *(unsigned*)&t;
    t = __float22bfloat162_rn(make_float2(a[2], a[3])); r.u[1] = *(unsigned*)&t;
    t = __float22bfloat162_rn(make_float2(b[0], b[1])); r.u[2] = *(unsigned*)&t;
    t = __float22bfloat162_rn(make_float2(b[2], b[3])); r.u[3] = *(unsigned*)&t;
    return r.v;
}
static __device__ __forceinline__ bf16x8 pack8f(float4 a, float4 b) {
    union { bf16x8 v; unsigned u[4]; } r;
    __hip_bfloat162 t;
    t = __float22bfloat162_rn(make_float2(a.x, a.y)); r.u[0] = *(unsigned*)&t;
    t = __float22bfloat162_rn(make_float2(a.z, a.w)); r.u[1] = *(unsigned*)&t;
    t = __float22bfloat162_rn(make_float2(b.x, b.y)); r.u[2] = *(unsigned*)&t;
    t = __float22bfloat162_rn(make_float2(b.z, b.w)); r.u[3] = *(unsigned*)&t;
    return r.v;
}

// async global->LDS, 16B per lane (LDS dest wave-uniform, +lane*16 implicit)
#define ASYNC16(gp, lp)                                                \
    __builtin_amdgcn_global_load_lds(                                  \
        (const __attribute__((address_space(1))) void*)(gp),           \
        (__attribute__((address_space(3))) void*)(lp), 16, 0, 0)

// ---------------------------------------------------------------------------
// Prep 1: x fp32 [M,K] -> bf16 same layout.
// ---------------------------------------------------------------------------
__global__ __launch_bounds__(256) void convert_x(
    const float* __restrict__ x, unsigned short* __restrict__ xb)
{
    int i = blockIdx.x * 256 + threadIdx.x;
    const float4* xp = (const float4*)x;
    float4 a = xp[i * 2], b = xp[i * 2 + 1];
    *(bf16x8*)&xb[i * 8] = pack8f(a, b);
}

// ---------------------------------------------------------------------------
// Prep 2: transpose-convert W [R][C] fp32 -> bf16 [C][R].
// ---------------------------------------------------------------------------
__global__ __launch_bounds__(256) void wtrans(
    const float* __restrict__ w, unsigned short* __restrict__ wt, int R, int C)
{
    __shared__ float tile[32][33];
    const int t = threadIdx.x;
    const int lr = t >> 5, lc = t & 31;
    const int r0 = blockIdx.y * 32, c0 = blockIdx.x * 32;
    #pragma unroll
    for (int p = 0; p < 4; ++p)
        tile[lr + p * 8][lc] = w[(size_t)(r0 + lr + p * 8) * C + c0 + lc];
    __syncthreads();
    #pragma unroll
    for (int p = 0; p < 4; ++p) {
        int oc = lr + p * 8;
        float v = tile[lc][oc];
        wt[(size_t)(c0 + oc) * R + r0 + lc] = f2bf(v);
    }
}

// ---------------------------------------------------------------------------
// Kernel 1: qkv = xb @ Wqkv^T + b (bf16 MFMA).
// R4: 128x128, BK=64, 2-slot LDS double-buffer. Per K-step:
//   STAGE(next -> slot^1)  (8 async global_load_lds, issued FIRST)
//   ds_read + 32 MFMA from slot   (covers the load latency)
//   vmcnt(0) + s_barrier          (one barrier per step; loads had ~2.5k cyc)
// WAR-safe: MFMAs consuming ds_reads precede the barrier (compiler lgkm
// waits), so all reads of `slot` are complete before the next step's stage
// writes it. Swizzle sigma(row)=row&7 over 16B chunks (conflict-free b128).
// ---------------------------------------------------------------------------
__global__ __launch_bounds__(256) void gemm_qkv_mfma(
    const unsigned short* __restrict__ xb,
    const unsigned short* __restrict__ wt,
    const float* __restrict__ bias,
    unsigned short* __restrict__ Qo, unsigned short* __restrict__ Ko,
    unsigned short* __restrict__ Vo)
{
    __shared__ __align__(16) unsigned short As[2][128 * 64];   // 2 x 16 KB
    __shared__ __align__(16) unsigned short Bs[2][128 * 64];   // 2 x 16 KB

    const int t = threadIdx.x;
    const int w = t >> 6, lane = t & 63;
    const int quad = lane >> 4, l15 = lane & 15;
    const int wm = w >> 1, wn = w & 1;
    const int m0 = blockIdx.y * 128;
    const int n0 = blockIdx.x * 128;
    const int srow = lane >> 3;            // 0..7: row within 8-row stripe
    const int sch  = lane & 7;             // 16B chunk slot within 128B row
    const int scw  = (sch ^ srow) * 8;     // swizzled global k-chunk (elems)
    const int rb   = l15 & 7;              // read swizzle base (= row&7)

    floatx4 acc[4][4];
    #pragma unroll
    for (int i = 0; i < 4; ++i)
        #pragma unroll
        for (int j = 0; j < 4; ++j) acc[i][j] = (floatx4){0.f, 0.f, 0.f, 0.f};

    const unsigned short* aG = &xb[(size_t)(m0 + w * 8 + srow) * EE + scw];
    const unsigned short* bG = &wt[(size_t)(n0 + w * 8 + srow) * EE + scw];

#define STAGE_QKV(kk, sl) do {                                              \
    _Pragma("unroll")                                                       \
    for (int p = 0; p < 4; ++p) {                                           \
        ASYNC16(aG + (kk) + (size_t)(p * 32) * EE,                          \
                &As[sl][(w * 8 + p * 32) * 64]);                            \
        ASYNC16(bG + (kk) + (size_t)(p * 32) * EE,                          \
                &Bs[sl][(w * 8 + p * 32) * 64]);                            \
    } } while (0)

    STAGE_QKV(0, 0);
    __asm__ __volatile__("s_waitcnt vmcnt(0)" ::: "memory");
    __builtin_amdgcn_s_barrier();

    #pragma unroll 1
    for (int kk = 0; kk < EE; kk += 64) {
        const int cur = (kk >> 6) & 1;
        if (kk + 64 < EE) STAGE_QKV(kk + 64, cur ^ 1);
        const unsigned short* Asl = As[cur];
        const unsigned short* Bsl = Bs[cur];
        #pragma unroll
        for (int s = 0; s < 2; ++s) {
            const int rsw = (((s << 2) | quad) ^ rb) * 8;
            bf16x8 af[4], bfv[4];
            #pragma unroll
            for (int i = 0; i < 4; ++i) {
                af[i]  = *(const bf16x8*)&Asl[(wm * 64 + i * 16 + l15) * 64 + rsw];
                bfv[i] = *(const bf16x8*)&Bsl[(wn * 64 + i * 16 + l15) * 64 + rsw];
            }
            __builtin_amdgcn_s_setprio(1);
            #pragma unroll
            for (int i = 0; i < 4; ++i)
                #pragma unroll
                for (int j = 0; j < 4; ++j)
                    acc[i][j] = __builtin_amdgcn_mfma_f32_16x16x32_bf16(
                        af[i], bfv[j], acc[i][j], 0, 0, 0);
            __builtin_amdgcn_s_setprio(0);
        }
        __asm__ __volatile__("s_waitcnt vmcnt(0)" ::: "memory");
        __builtin_amdgcn_s_barrier();
    }
#undef STAGE_QKV

    const int mb = m0 + wm * 64;
    const int nb = n0 + wn * 64;
    #pragma unroll
    for (int i = 0; i < 4; ++i) {
        #pragma unroll
        for (int j = 0; j < 4; ++j) {
            int nc = nb + j * 16;
            int which = nc >> 10;
            int e0 = nc & 1023;
            int h  = e0 >> 6;
            int d0 = e0 & 63;
            float bv = bias[nc + l15];
            #pragma unroll
            for (int r = 0; r < 4; ++r) {
                int m = mb + i * 16 + quad * 4 + r;
                int b = m >> 10, n = m & 1023;
                size_t off = ((size_t)(b * HH + h) * NN + n) * DD + d0 + l15;
                float v = acc[i][j][r] + bv;
                if (which == 0)      Qo[off] = f2bf(v * SCALE_Q);
                else if (which == 1) Ko[off] = f2bf(v);
                else                 Vo[off] = f2bf(v);
            }
        }
    }
}

// ---------------------------------------------------------------------------
// Prep 3 (post-qkv): V [B,H,N,D] bf16 -> Vt [B,H,D,N] bf16.
// ---------------------------------------------------------------------------
__global__ __launch_bounds__(256) void vtrans(
    const unsigned short* __restrict__ V, unsigned short* __restrict__ Vt)
{
    __shared__ __align__(16) unsigned short tile[64][72];   // [d][n]
    const int t  = threadIdx.x;
    const int bh = blockIdx.x;       // 0..255
    const int n0 = blockIdx.y * 64;  // 16 tiles
    const int r  = t >> 2, c = t & 3;

    const unsigned short* src = &V[((size_t)bh * NN + n0 + r) * DD + c * 16];
    bf16x8 v0 = *(const bf16x8*)&src[0];
    bf16x8 v1 = *(const bf16x8*)&src[8];
    #pragma unroll
    for (int k = 0; k < 8; ++k) tile[c * 16 + k][r]     = v0[k];
    #pragma unroll
    for (int k = 0; k < 8; ++k) tile[c * 16 + 8 + k][r] = v1[k];
    __syncthreads();

    unsigned short* dst = &Vt[((size_t)bh * DD + r) * NN + n0 + c * 16];
    *(bf16x8*)&dst[0] = *(const bf16x8*)&tile[r][c * 16];
    *(bf16x8*)&dst[8] = *(const bf16x8*)&tile[r][c * 16 + 8];
}

// ---------------------------------------------------------------------------
// Kernel 2: transposed-score flash attention, bf16 MFMA (unchanged from R2:
// raw v_exp_f32, MFMA-ones row-sum, setprio around MFMA clusters).
// ---------------------------------------------------------------------------
__global__ __launch_bounds__(256) void attn_mfma(
    const unsigned short* __restrict__ Q,
    const unsigned short* __restrict__ K,
    const unsigned short* __restrict__ Vt,
    unsigned short* __restrict__ O)
{
    __shared__ __align__(16) unsigned short Ks[64 * 64];  // [key][d], swizzled
    __shared__ __align__(16) unsigned short Vs[64 * 64];  // [d][kappa], swizzled

    const int t    = threadIdx.x;
    const int w    = t >> 6;
    const int quad = (t >> 4) & 3;
    const int l15  = t & 15;
    const int i    = blockIdx.x;                 // 0..2047
    const int bh   = ((i >> 6) << 3) | (i & 7);  // XCD-local bh windows
    const int qt   = (i >> 3) & 7;

    const unsigned short* Qg = Q  + (size_t)bh * NN * DD;
    const unsigned short* Kg = K  + (size_t)bh * NN * DD;
    const unsigned short* Vg = Vt + (size_t)bh * DD * NN;

    const int q0 = qt * 128 + w * 32;

    bf16x8 qf[2][2];
    #pragma unroll
    for (int a = 0; a < 2; ++a) {
        qf[a][0] = *(const bf16x8*)&Qg[(size_t)(q0 + a * 16 + l15) * DD + quad * 8];
        qf[a][1] = *(const bf16x8*)&Qg[(size_t)(q0 + a * 16 + l15) * DD + 32 + quad * 8];
    }

    // all-ones A-fragment: mfma(ones, P) -> every output element = column sum
    bf16x8 onesA;
    #pragma unroll
    for (int z = 0; z < 8; ++z) onesA[z] = (short)0x3F80;  // bf16 1.0

    floatx4 oa[2][4];
    #pragma unroll
    for (int a = 0; a < 2; ++a)
        #pragma unroll
        for (int jd = 0; jd < 4; ++jd) oa[a][jd] = (floatx4){0.f, 0.f, 0.f, 0.f};
    floatx4 ls[2];
    ls[0] = (floatx4){0.f, 0.f, 0.f, 0.f};
    ls[1] = (floatx4){0.f, 0.f, 0.f, 0.f};

    const int srow = t >> 2;
    const int sc   = t & 3;
    const int swz  = srow & 7;
    const int cbase = ((quad ^ (l15 & 7)) << 3);

    bf16x8 kr0, kr1, vr0, vr1;
    {
        const unsigned short* kg = &Kg[(size_t)srow * DD + sc * 16];
        kr0 = *(const bf16x8*)&kg[0];
        kr1 = *(const bf16x8*)&kg[8];
        const unsigned short* vg = &Vg[(size_t)srow * NN + sc * 16];
        vr0 = *(const bf16x8*)&vg[0];
        vr1 = *(const bf16x8*)&vg[8];
    }

    for (int kt = 0; kt < 16; ++kt) {
        __syncthreads();
        *(bf16x8*)&Ks[srow * 64 + (((2 * sc + 0) ^ swz) << 3)] = kr0;
        *(bf16x8*)&Ks[srow * 64 + (((2 * sc + 1) ^ swz) << 3)] = kr1;
        {
            bf16x4 h[4];
            h[0] = (bf16x4){vr0[0], vr0[1], vr0[2], vr0[3]};
            h[1] = (bf16x4){vr0[4], vr0[5], vr0[6], vr0[7]};
            h[2] = (bf16x4){vr1[0], vr1[1], vr1[2], vr1[3]};
            h[3] = (bf16x4){vr1[4], vr1[5], vr1[6], vr1[7]};
            #pragma unroll
            for (int q = 0; q < 4; ++q) {
                int col = ((((sc >> 1) * 4 + q) ^ swz) << 3) + ((sc & 1) << 2);
                *(bf16x4*)&Vs[srow * 64 + col] = h[q];
            }
        }
        __syncthreads();

        if (kt < 15) {
            const unsigned short* kg =
                &Kg[(size_t)((kt + 1) * 64 + srow) * DD + sc * 16];
            kr0 = *(const bf16x8*)&kg[0];
            kr1 = *(const bf16x8*)&kg[8];
            const unsigned short* vg =
                &Vg[(size_t)srow * NN + (kt + 1) * 64 + sc * 16];
            vr0 = *(const bf16x8*)&vg[0];
            vr1 = *(const bf16x8*)&vg[8];
        }

        floatx4 sa[2][4];
        #pragma unroll
        for (int a = 0; a < 2; ++a)
            #pragma unroll
            for (int tt = 0; tt < 4; ++tt) sa[a][tt] = (floatx4){0.f, 0.f, 0.f, 0.f};
        __builtin_amdgcn_s_setprio(1);
        #pragma unroll
        for (int tt = 0; tt < 4; ++tt) {
            const unsigned short* kb = &Ks[(tt * 16 + l15) * 64];
            bf16x8 kf0 = *(const bf16x8*)&kb[cbase];
            bf16x8 kf1 = *(const bf16x8*)&kb[cbase ^ 32];
            #pragma unroll
            for (int a = 0; a < 2; ++a) {
                sa[a][tt] = __builtin_amdgcn_mfma_f32_16x16x32_bf16(
                    kf0, qf[a][0], sa[a][tt], 0, 0, 0);
                sa[a][tt] = __builtin_amdgcn_mfma_f32_16x16x32_bf16(
                    kf1, qf[a][1], sa[a][tt], 0, 0, 0);
            }
        }
        __builtin_amdgcn_s_setprio(0);

        bf16x8 pf[2][2];
        #pragma unroll
        for (int a = 0; a < 2; ++a) {
            floatx4 pe[4];
            #pragma unroll
            for (int tt = 0; tt < 4; ++tt) {
                #pragma unroll
                for (int r = 0; r < 4; ++r)
                    pe[tt][r] = fast_exp2(sa[a][tt][r]);
            }
            pf[a][0] = pack8v(pe[0], pe[1]);
            pf[a][1] = pack8v(pe[2], pe[3]);
        }

        __builtin_amdgcn_s_setprio(1);
        // row-sum of P via MFMA (replaces 32 serial f32 adds per lane)
        #pragma unroll
        for (int a = 0; a < 2; ++a) {
            ls[a] = __builtin_amdgcn_mfma_f32_16x16x32_bf16(
                onesA, pf[a][0], ls[a], 0, 0, 0);
            ls[a] = __builtin_amdgcn_mfma_f32_16x16x32_bf16(
                onesA, pf[a][1], ls[a], 0, 0, 0);
        }
        #pragma unroll
        for (int jd = 0; jd < 4; ++jd) {
            const unsigned short* vb = &Vs[(jd * 16 + l15) * 64];
            bf16x8 vf0 = *(const bf16x8*)&vb[cbase];
            bf16x8 vf1 = *(const bf16x8*)&vb[cbase ^ 32];
            #pragma unroll
            for (int a = 0; a < 2; ++a) {
                oa[a][jd] = __builtin_amdgcn_mfma_f32_16x16x32_bf16(
                    vf0, pf[a][0], oa[a][jd], 0, 0, 0);
                oa[a][jd] = __builtin_amdgcn_mfma_f32_16x16x32_bf16(
                    vf1, pf[a][1], oa[a][jd], 0, 0, 0);
            }
        }
        __builtin_amdgcn_s_setprio(0);
    }

    const int b = bh >> 4, h = bh & 15;
    #pragma unroll
    for (int a = 0; a < 2; ++a) {
        float inv = 1.f / ls[a][0];   // every row of ls holds the full sum
        int n = q0 + a * 16 + l15;
        size_t base = (size_t)(b * NN + n) * EE + h * DD;
        #pragma unroll
        for (int jd = 0; jd < 4; ++jd) {
            bf16x4 v;
            v[0] = (short)f2bf(oa[a][jd][0] * inv);
            v[1] = (short)f2bf(oa[a][jd][1] * inv);
            v[2] = (short)f2bf(oa[a][jd][2] * inv);
            v[3] = (short)f2bf(oa[a][jd][3] * inv);
            *(bf16x4*)&O[base + jd * 16 + quad * 4] = v;
        }
    }
}

// ---------------------------------------------------------------------------
// Kernel 3: out = O @ Wp^T + b — 128x128, BK=64, 2-slot dbuf, fp32 out.
// ---------------------------------------------------------------------------
__global__ __launch_bounds__(256) void gemm_proj_mfma(
    const unsigned short* __restrict__ Ob,
    const unsigned short* __restrict__ Bp,
    const float* __restrict__ bias, float* __restrict__ out)
{
    __shared__ __align__(16) unsigned short As[2][128 * 64];
    __shared__ __align__(16) unsigned short Bs[2][128 * 64];

    const int t = threadIdx.x;
    const int w = t >> 6, lane = t & 63;
    const int quad = lane >> 4, l15 = lane & 15;
    const int wm = w >> 1, wn = w & 1;
    const int m0 = blockIdx.y * 128;
    const int n0 = blockIdx.x * 128;
    const int srow = lane >> 3;
    const int sch  = lane & 7;
    const int scw  = (sch ^ srow) * 8;
    const int rb   = l15 & 7;

    floatx4 acc[4][4];
    #pragma unroll
    for (int i = 0; i < 4; ++i)
        #pragma unroll
        for (int j = 0; j < 4; ++j) acc[i][j] = (floatx4){0.f, 0.f, 0.f, 0.f};

    const unsigned short* aG = &Ob[(size_t)(m0 + w * 8 + srow) * EE + scw];
    const unsigned short* bG = &Bp[(size_t)(n0 + w * 8 + srow) * EE + scw];

#define STAGE_PRJ(kk, sl) do {                                              \
    _Pragma("unroll")                                                       \
    for (int p = 0; p < 4; ++p) {                                           \
        ASYNC16(aG + (kk) + (size_t)(p * 32) * EE,                          \
                &As[sl][(w * 8 + p * 32) * 64]);                            \
        ASYNC16(bG + (kk) + (size_t)(p * 32) * EE,                          \
                &Bs[sl][(w * 8 + p * 32) * 64]);                            \
    } } while (0)

    STAGE_PRJ(0, 0);
    __asm__ __volatile__("s_waitcnt vmcnt(0)" ::: "memory");
    __builtin_amdgcn_s_barrier();

    #pragma unroll 1
    for (int kk = 0; kk < EE; kk += 64) {
        const int cur = (kk >> 6) & 1;
        if (kk + 64 < EE) STAGE_PRJ(kk + 64, cur ^ 1);
        const unsigned short* Asl = As[cur];
        const unsigned short* Bsl = Bs[cur];
        #pragma unroll
        for (int s = 0; s < 2; ++s) {
            const int rsw = (((s << 2) | quad) ^ rb) * 8;
            bf16x8 af[4], bfv[4];
            #pragma unroll
            for (int i = 0; i < 4; ++i) {
                af[i]  = *(const bf16x8*)&Asl[(wm * 64 + i * 16 + l15) * 64 + rsw];
                bfv[i] = *(const bf16x8*)&Bsl[(wn * 64 + i * 16 + l15) * 64 + rsw];
            }
            __builtin_amdgcn_s_setprio(1);
            #pragma unroll
            for (int i = 0; i < 4; ++i)
                #pragma unroll
                for (int j = 0; j < 4; ++j)
                    acc[i][j] = __builtin_amdgcn_mfma_f32_16x16x32_bf16(
                        af[i], bfv[j], acc[i][j], 0, 0, 0);
            __builtin_amdgcn_s_setprio(0);
        }
        __asm__ __volatile__("s_waitcnt vmcnt(0)" ::: "memory");
        __builtin_amdgcn_s_barrier();
    }
#undef STAGE_PRJ

    const int mb = m0 + wm * 64;
    const int nb = n0 + wn * 64;
    #pragma unroll
    for (int i = 0; i < 4; ++i) {
        #pragma unroll
        for (int j = 0; j < 4; ++j) {
            float bv = bias[nb + j * 16 + l15];
            #pragma unroll
            for (int r = 0; r < 4; ++r) {
                int mrow = mb + i * 16 + quad * 4 + r;
                out[(size_t)mrow * EE + nb + j * 16 + l15] = acc[i][j][r] + bv;
            }
        }
    }
}

// ---------------------------------------------------------------------------
extern "C" void kernel_launch(void* const* d_in, const int* in_sizes, int n_in,
                              void* d_out, int out_size, void* d_ws, size_t ws_size,
                              hipStream_t stream) {
    const float* x     = (const float*)d_in[0];
    const float* Wqkv  = (const float*)d_in[1];
    const float* bqkv  = (const float*)d_in[2];
    const float* Wproj = (const float*)d_in[3];
    const float* bproj = (const float*)d_in[4];
    float* out = (float*)d_out;

    const size_t BHND = (size_t)BB * HH * NN * DD;      // 16777216
    unsigned short* Q   = (unsigned short*)d_ws;
    unsigned short* K   = Q   + BHND;
    unsigned short* Vn  = K   + BHND;                   // V natural [B,H,N,D]
    unsigned short* Vt  = Vn  + BHND;                   // V^T [B,H,D,N]
    unsigned short* Ob  = Vt  + BHND;                   // [16384][1024] bf16
    unsigned short* xb  = Ob  + BHND;
    unsigned short* Wqt = xb  + BHND;                   // [3072][1024]
    unsigned short* Wpt = Wqt + (size_t)THREE_E * EE;   // [1024][1024]

    dim3 blk(256);
    convert_x<<<dim3(M_TOTAL * EE / (256 * 8)), blk, 0, stream>>>(x, xb);
    wtrans<<<dim3(THREE_E / 32, EE / 32), blk, 0, stream>>>(Wqkv, Wqt, EE, THREE_E);
    wtrans<<<dim3(EE / 32, EE / 32), blk, 0, stream>>>(Wproj, Wpt, EE, EE);

    gemm_qkv_mfma<<<dim3(THREE_E / 128, M_TOTAL / 128), blk, 0, stream>>>(
        xb, Wqt, bqkv, Q, K, Vn);
    vtrans<<<dim3(BB * HH, NN / 64), blk, 0, stream>>>(Vn, Vt);
    attn_mfma<<<dim3(BB * HH * NN / 128), blk, 0, stream>>>(Q, K, Vt, Ob);
    gemm_proj_mfma<<<dim3(EE / 128, M_TOTAL / 128), blk, 0, stream>>>(
        Ob, Wpt, bproj, out);
}

// Round 5
// 402.356 us; speedup vs baseline: 1.0201x; 1.0201x over previous
//
#include <hip/hip_runtime.h>
#include <hip/hip_bf16.h>
#include <math.h>

// Problem constants
#define BB 16
#define NN 1024
#define EE 1024
#define HH 16
#define DD 64
#define THREE_E 3072
#define M_TOTAL (BB * NN)   // 16384

typedef __attribute__((ext_vector_type(8))) short bf16x8;   // 8 bf16 = 4 VGPR
typedef __attribute__((ext_vector_type(4))) short bf16x4;   // 4 bf16 = 2 VGPR
typedef __attribute__((ext_vector_type(4))) float floatx4;  // MFMA C/D

// Q pre-scale: 1/sqrt(64) * log2(e)  (scores land in exp2 domain)
#define SCALE_Q 0.18033688011112042f

static __device__ __forceinline__ unsigned short f2bf(float f) {
    union { float f; unsigned u; } x; x.f = f;
    unsigned r = x.u + 0x7fffu + ((x.u >> 16) & 1u);
    return (unsigned short)(r >> 16);
}

// raw v_exp_f32 — scores are bounded, skip OCML denormal guards
static __device__ __forceinline__ float fast_exp2(float x) {
#if __has_builtin(__builtin_amdgcn_exp2f)
    return __builtin_amdgcn_exp2f(x);
#else
    float r; __asm__("v_exp_f32 %0, %1" : "=v"(r) : "v"(x)); return r;
#endif
}

// pack 2x floatx4 -> bf16x8 via v_cvt_pk_bf16_f32 (RNE)
static __device__ __forceinline__ bf16x8 pack8v(floatx4 a, floatx4 b) {
    union { bf16x8 v; unsigned u[4]; } r;
    __hip_bfloat162 t;
    t = __float22bfloat162_rn(make_float2(a[0], a[1])); r.u[0] = *(unsigned*)&t;
    t = __float22bfloat162_rn(make_float2(a[2], a[3])); r.u[1] = *(unsigned*)&t;
    t = __float22bfloat162_rn(make_float2(b[0], b[1])); r.u[2] = *(unsigned*)&t;
    t = __float22bfloat162_rn(make_float2(b[2], b[3])); r.u[3] = *(unsigned*)&t;
    return r.v;
}
static __device__ __forceinline__ bf16x8 pack8f(float4 a, float4 b) {
    union { bf16x8 v; unsigned u[4]; } r;
    __hip_bfloat162 t;
    t = __float22bfloat162_rn(make_float2(a.x, a.y)); r.u[0] = *(unsigned*)&t;
    t = __float22bfloat162_rn(make_float2(a.z, a.w)); r.u[1] = *(unsigned*)&t;
    t = __float22bfloat162_rn(make_float2(b.x, b.y)); r.u[2] = *(unsigned*)&t;
    t = __float22bfloat162_rn(make_float2(b.z, b.w)); r.u[3] = *(unsigned*)&t;
    return r.v;
}

// async global->LDS, 16B per lane (LDS dest wave-uniform, +lane*16 implicit)
#define ASYNC16(gp, lp)                                                \
    __builtin_amdgcn_global_load_lds(                                  \
        (const __attribute__((address_space(1))) void*)(gp),           \
        (__attribute__((address_space(3))) void*)(lp), 16, 0, 0)

#define DRAIN_VMEM() __asm__ __volatile__("s_waitcnt vmcnt(0)" ::: "memory")

// ---------------------------------------------------------------------------
// Merged prep: convert_x (blocks 0..8191), wtrans Wqkv (8192..11263),
// wtrans Wproj (11264..12287). One dispatch instead of three.
// ---------------------------------------------------------------------------
__global__ __launch_bounds__(256) void prep_all(
    const float* __restrict__ x, unsigned short* __restrict__ xb,
    const float* __restrict__ Wqkv, unsigned short* __restrict__ Wqt,
    const float* __restrict__ Wproj, unsigned short* __restrict__ Wpt)
{
    __shared__ float tile[32][33];
    const int bid = blockIdx.x;
    const int t = threadIdx.x;

    if (bid < 8192) {
        int i = bid * 256 + t;
        const float4* xp = (const float4*)x;
        float4 a = xp[i * 2], b = xp[i * 2 + 1];
        *(bf16x8*)&xb[i * 8] = pack8f(a, b);
        return;
    }

    const float* w; unsigned short* wt; int R, C, bx, by;
    if (bid < 8192 + 3072) {
        int local = bid - 8192;
        bx = local % 96; by = local / 96;
        w = Wqkv; wt = Wqt; R = EE; C = THREE_E;
    } else {
        int local = bid - 11264;
        bx = local % 32; by = local / 32;
        w = Wproj; wt = Wpt; R = EE; C = EE;
    }
    const int lr = t >> 5, lc = t & 31;
    const int r0 = by * 32, c0 = bx * 32;
    #pragma unroll
    for (int p = 0; p < 4; ++p)
        tile[lr + p * 8][lc] = w[(size_t)(r0 + lr + p * 8) * C + c0 + lc];
    __syncthreads();
    #pragma unroll
    for (int p = 0; p < 4; ++p) {
        int oc = lr + p * 8;
        float v = tile[lc][oc];
        wt[(size_t)(c0 + oc) * R + r0 + lc] = f2bf(v);
    }
}

// ---------------------------------------------------------------------------
// Kernel 1: qkv = xb @ Wqkv^T + b (bf16 MFMA).
// R3-proven structure (125.4us): 128x128, BK=64, single-buffer.
// Occupancy-driven implicit overlap beats explicit dbuf here (R1/R4 evidence).
// Swizzle sigma(row)=row&7 over 16B chunks (conflict-free b128 reads).
// ---------------------------------------------------------------------------
__global__ __launch_bounds__(256) void gemm_qkv_mfma(
    const unsigned short* __restrict__ xb,
    const unsigned short* __restrict__ wt,
    const float* __restrict__ bias,
    unsigned short* __restrict__ Qo, unsigned short* __restrict__ Ko,
    unsigned short* __restrict__ Vo)
{
    __shared__ __align__(16) unsigned short As[128 * 64];   // 16 KB
    __shared__ __align__(16) unsigned short Bs[128 * 64];   // 16 KB

    const int t = threadIdx.x;
    const int w = t >> 6, lane = t & 63;
    const int quad = lane >> 4, l15 = lane & 15;
    const int wm = w >> 1, wn = w & 1;
    const int m0 = blockIdx.y * 128;
    const int n0 = blockIdx.x * 128;
    const int srow = lane >> 3;            // 0..7: row within 8-row stripe
    const int sch  = lane & 7;             // 16B chunk slot within 128B row
    const int scw  = (sch ^ srow) * 8;     // swizzled global k-chunk (elems)
    const int rb   = l15 & 7;              // read swizzle base (= row&7)

    floatx4 acc[4][4];
    #pragma unroll
    for (int i = 0; i < 4; ++i)
        #pragma unroll
        for (int j = 0; j < 4; ++j) acc[i][j] = (floatx4){0.f, 0.f, 0.f, 0.f};

    const unsigned short* aG = &xb[(size_t)(m0 + w * 8 + srow) * EE + scw];
    const unsigned short* bG = &wt[(size_t)(n0 + w * 8 + srow) * EE + scw];

    for (int kk = 0; kk < EE; kk += 64) {
        #pragma unroll
        for (int p = 0; p < 4; ++p) {
            ASYNC16(aG + kk + (size_t)(p * 32) * EE, &As[(w * 8 + p * 32) * 64]);
            ASYNC16(bG + kk + (size_t)(p * 32) * EE, &Bs[(w * 8 + p * 32) * 64]);
        }
        DRAIN_VMEM();
        __syncthreads();

        #pragma unroll
        for (int s = 0; s < 2; ++s) {
            const int rsw = (((s << 2) | quad) ^ rb) * 8;
            bf16x8 af[4], bf[4];
            #pragma unroll
            for (int i = 0; i < 4; ++i) {
                af[i] = *(const bf16x8*)&As[(wm * 64 + i * 16 + l15) * 64 + rsw];
                bf[i] = *(const bf16x8*)&Bs[(wn * 64 + i * 16 + l15) * 64 + rsw];
            }
            #pragma unroll
            for (int i = 0; i < 4; ++i)
                #pragma unroll
                for (int j = 0; j < 4; ++j)
                    acc[i][j] = __builtin_amdgcn_mfma_f32_16x16x32_bf16(
                        af[i], bf[j], acc[i][j], 0, 0, 0);
        }
        __syncthreads();
    }

    const int mb = m0 + wm * 64;
    const int nb = n0 + wn * 64;
    #pragma unroll
    for (int i = 0; i < 4; ++i) {
        #pragma unroll
        for (int j = 0; j < 4; ++j) {
            int nc = nb + j * 16;
            int which = nc >> 10;
            int e0 = nc & 1023;
            int h  = e0 >> 6;
            int d0 = e0 & 63;
            float bv = bias[nc + l15];
            #pragma unroll
            for (int r = 0; r < 4; ++r) {
                int m = mb + i * 16 + quad * 4 + r;
                int b = m >> 10, n = m & 1023;
                size_t off = ((size_t)(b * HH + h) * NN + n) * DD + d0 + l15;
                float v = acc[i][j][r] + bv;
                if (which == 0)      Qo[off] = f2bf(v * SCALE_Q);
                else if (which == 1) Ko[off] = f2bf(v);
                else                 Vo[off] = f2bf(v);
            }
        }
    }
}

// ---------------------------------------------------------------------------
// Prep 3 (post-qkv): V [B,H,N,D] bf16 -> Vt [B,H,D,N] bf16.
// ---------------------------------------------------------------------------
__global__ __launch_bounds__(256) void vtrans(
    const unsigned short* __restrict__ V, unsigned short* __restrict__ Vt)
{
    __shared__ __align__(16) unsigned short tile[64][72];   // [d][n]
    const int t  = threadIdx.x;
    const int bh = blockIdx.x;       // 0..255
    const int n0 = blockIdx.y * 64;  // 16 tiles
    const int r  = t >> 2, c = t & 3;

    const unsigned short* src = &V[((size_t)bh * NN + n0 + r) * DD + c * 16];
    bf16x8 v0 = *(const bf16x8*)&src[0];
    bf16x8 v1 = *(const bf16x8*)&src[8];
    #pragma unroll
    for (int k = 0; k < 8; ++k) tile[c * 16 + k][r]     = v0[k];
    #pragma unroll
    for (int k = 0; k < 8; ++k) tile[c * 16 + 8 + k][r] = v1[k];
    __syncthreads();

    unsigned short* dst = &Vt[((size_t)bh * DD + r) * NN + n0 + c * 16];
    *(bf16x8*)&dst[0] = *(const bf16x8*)&tile[r][c * 16];
    *(bf16x8*)&dst[8] = *(const bf16x8*)&tile[r][c * 16 + 8];
}

// ---------------------------------------------------------------------------
// Kernel 2: transposed-score flash attention, bf16 MFMA.
// R5: double-buffered K/V LDS (2 slots) + 2-deep register pipeline (A/B
// sets, statically indexed). ONE __syncthreads per K-tile (16 vs 32) and
// the LDS-write overlaps compute on the other slot instead of stalling all
// waves between two barriers. Softmax: raw v_exp_f32, MFMA-ones row-sum.
// ---------------------------------------------------------------------------
__global__ __launch_bounds__(256) void attn_mfma(
    const unsigned short* __restrict__ Q,
    const unsigned short* __restrict__ K,
    const unsigned short* __restrict__ Vt,
    unsigned short* __restrict__ O)
{
    __shared__ __align__(16) unsigned short Ks[2][64 * 64];  // [key][d], swizzled
    __shared__ __align__(16) unsigned short Vs[2][64 * 64];  // [d][kappa], swizzled

    const int t    = threadIdx.x;
    const int w    = t >> 6;
    const int quad = (t >> 4) & 3;
    const int l15  = t & 15;
    const int i    = blockIdx.x;                 // 0..2047
    const int bh   = ((i >> 6) << 3) | (i & 7);  // XCD-local bh windows
    const int qt   = (i >> 3) & 7;

    const unsigned short* Qg = Q  + (size_t)bh * NN * DD;
    const unsigned short* Kg = K  + (size_t)bh * NN * DD;
    const unsigned short* Vg = Vt + (size_t)bh * DD * NN;

    const int q0 = qt * 128 + w * 32;

    bf16x8 qf[2][2];
    #pragma unroll
    for (int a = 0; a < 2; ++a) {
        qf[a][0] = *(const bf16x8*)&Qg[(size_t)(q0 + a * 16 + l15) * DD + quad * 8];
        qf[a][1] = *(const bf16x8*)&Qg[(size_t)(q0 + a * 16 + l15) * DD + 32 + quad * 8];
    }

    // all-ones A-fragment: mfma(ones, P) -> every output element = column sum
    bf16x8 onesA;
    #pragma unroll
    for (int z = 0; z < 8; ++z) onesA[z] = (short)0x3F80;  // bf16 1.0

    floatx4 oa[2][4];
    #pragma unroll
    for (int a = 0; a < 2; ++a)
        #pragma unroll
        for (int jd = 0; jd < 4; ++jd) oa[a][jd] = (floatx4){0.f, 0.f, 0.f, 0.f};
    floatx4 ls[2];
    ls[0] = (floatx4){0.f, 0.f, 0.f, 0.f};
    ls[1] = (floatx4){0.f, 0.f, 0.f, 0.f};

    const int srow = t >> 2;
    const int sc   = t & 3;
    const int swz  = srow & 7;
    const int cbase = ((quad ^ (l15 & 7)) << 3);

    bf16x8 krA0, krA1, vrA0, vrA1;   // reg set A
    bf16x8 krB0, krB1, vrB0, vrB1;   // reg set B

#define LOADKV(T, k0, k1, v0, v1) do {                                      \
    const unsigned short* kg_ = &Kg[(size_t)((T) * 64 + srow) * DD + sc * 16];\
    k0 = *(const bf16x8*)&kg_[0];                                           \
    k1 = *(const bf16x8*)&kg_[8];                                           \
    const unsigned short* vg_ = &Vg[(size_t)srow * NN + (T) * 64 + sc * 16];\
    v0 = *(const bf16x8*)&vg_[0];                                           \
    v1 = *(const bf16x8*)&vg_[8]; } while (0)

#define WRITEKV(S, k0, k1, v0, v1) do {                                     \
    *(bf16x8*)&Ks[S][srow * 64 + (((2 * sc + 0) ^ swz) << 3)] = k0;         \
    *(bf16x8*)&Ks[S][srow * 64 + (((2 * sc + 1) ^ swz) << 3)] = k1;         \
    bf16x4 h0_ = (bf16x4){v0[0], v0[1], v0[2], v0[3]};                      \
    bf16x4 h1_ = (bf16x4){v0[4], v0[5], v0[6], v0[7]};                      \
    bf16x4 h2_ = (bf16x4){v1[0], v1[1], v1[2], v1[3]};                      \
    bf16x4 h3_ = (bf16x4){v1[4], v1[5], v1[6], v1[7]};                      \
    *(bf16x4*)&Vs[S][srow * 64 + (((((sc >> 1) * 4 + 0)) ^ swz) << 3) + ((sc & 1) << 2)] = h0_; \
    *(bf16x4*)&Vs[S][srow * 64 + (((((sc >> 1) * 4 + 1)) ^ swz) << 3) + ((sc & 1) << 2)] = h1_; \
    *(bf16x4*)&Vs[S][srow * 64 + (((((sc >> 1) * 4 + 2)) ^ swz) << 3) + ((sc & 1) << 2)] = h2_; \
    *(bf16x4*)&Vs[S][srow * 64 + (((((sc >> 1) * 4 + 3)) ^ swz) << 3) + ((sc & 1) << 2)] = h3_; \
    } while (0)

#define COMPUTE(S) do {                                                     \
    floatx4 sa[2][4];                                                       \
    _Pragma("unroll")                                                       \
    for (int a = 0; a < 2; ++a)                                             \
        _Pragma("unroll")                                                   \
        for (int tt = 0; tt < 4; ++tt) sa[a][tt] = (floatx4){0.f,0.f,0.f,0.f};\
    __builtin_amdgcn_s_setprio(1);                                          \
    _Pragma("unroll")                                                       \
    for (int tt = 0; tt < 4; ++tt) {                                        \
        const unsigned short* kb = &Ks[S][(tt * 16 + l15) * 64];            \
        bf16x8 kf0 = *(const bf16x8*)&kb[cbase];                            \
        bf16x8 kf1 = *(const bf16x8*)&kb[cbase ^ 32];                       \
        _Pragma("unroll")                                                   \
        for (int a = 0; a < 2; ++a) {                                       \
            sa[a][tt] = __builtin_amdgcn_mfma_f32_16x16x32_bf16(            \
                kf0, qf[a][0], sa[a][tt], 0, 0, 0);                         \
            sa[a][tt] = __builtin_amdgcn_mfma_f32_16x16x32_bf16(            \
                kf1, qf[a][1], sa[a][tt], 0, 0, 0);                         \
        }                                                                   \
    }                                                                       \
    __builtin_amdgcn_s_setprio(0);                                          \
    bf16x8 pf[2][2];                                                        \
    _Pragma("unroll")                                                       \
    for (int a = 0; a < 2; ++a) {                                           \
        floatx4 pe[4];                                                      \
        _Pragma("unroll")                                                   \
        for (int tt = 0; tt < 4; ++tt) {                                    \
            _Pragma("unroll")                                               \
            for (int r = 0; r < 4; ++r)                                     \
                pe[tt][r] = fast_exp2(sa[a][tt][r]);                        \
        }                                                                   \
        pf[a][0] = pack8v(pe[0], pe[1]);                                    \
        pf[a][1] = pack8v(pe[2], pe[3]);                                    \
    }                                                                       \
    __builtin_amdgcn_s_setprio(1);                                          \
    _Pragma("unroll")                                                       \
    for (int a = 0; a < 2; ++a) {                                           \
        ls[a] = __builtin_amdgcn_mfma_f32_16x16x32_bf16(                    \
            onesA, pf[a][0], ls[a], 0, 0, 0);                               \
        ls[a] = __builtin_amdgcn_mfma_f32_16x16x32_bf16(                    \
            onesA, pf[a][1], ls[a], 0, 0, 0);                               \
    }                                                                       \
    _Pragma("unroll")                                                       \
    for (int jd = 0; jd < 4; ++jd) {                                        \
        const unsigned short* vb = &Vs[S][(jd * 16 + l15) * 64];            \
        bf16x8 vf0 = *(const bf16x8*)&vb[cbase];                            \
        bf16x8 vf1 = *(const bf16x8*)&vb[cbase ^ 32];                       \
        _Pragma("unroll")                                                   \
        for (int a = 0; a < 2; ++a) {                                       \
            oa[a][jd] = __builtin_amdgcn_mfma_f32_16x16x32_bf16(            \
                vf0, pf[a][0], oa[a][jd], 0, 0, 0);                         \
            oa[a][jd] = __builtin_amdgcn_mfma_f32_16x16x32_bf16(            \
                vf1, pf[a][1], oa[a][jd], 0, 0, 0);                         \
        }                                                                   \
    }                                                                       \
    __builtin_amdgcn_s_setprio(0); } while (0)

    // prologue: tile0 -> regs A -> slot0; tile1 -> regs B (in flight)
    LOADKV(0, krA0, krA1, vrA0, vrA1);
    WRITEKV(0, krA0, krA1, vrA0, vrA1);   // compiler waits vmcnt for data regs
    LOADKV(1, krB0, krB1, vrB0, vrB1);
    __syncthreads();                       // slot0 visible; tile1 regs valid

    #pragma unroll 1
    for (int p = 0; p < 8; ++p) {
        // even tile e = 2p: compute slot0; write tile e+1 (B) -> slot1
        WRITEKV(1, krB0, krB1, vrB0, vrB1);
        if (p < 7) LOADKV(2 * p + 2, krA0, krA1, vrA0, vrA1);
        COMPUTE(0);
        __syncthreads();                   // slot1 visible; A-regs valid
        // odd tile o = 2p+1: compute slot1; write tile o+1 (A) -> slot0
        if (p < 7) {
            WRITEKV(0, krA0, krA1, vrA0, vrA1);
            LOADKV(2 * p + 3, krB0, krB1, vrB0, vrB1);
        }
        COMPUTE(1);
        __syncthreads();                   // slot0 visible; B-regs valid
    }
#undef LOADKV
#undef WRITEKV
#undef COMPUTE

    const int b = bh >> 4, h = bh & 15;
    #pragma unroll
    for (int a = 0; a < 2; ++a) {
        float inv = 1.f / ls[a][0];   // every row of ls holds the full sum
        int n = q0 + a * 16 + l15;
        size_t base = (size_t)(b * NN + n) * EE + h * DD;
        #pragma unroll
        for (int jd = 0; jd < 4; ++jd) {
            bf16x4 v;
            v[0] = (short)f2bf(oa[a][jd][0] * inv);
            v[1] = (short)f2bf(oa[a][jd][1] * inv);
            v[2] = (short)f2bf(oa[a][jd][2] * inv);
            v[3] = (short)f2bf(oa[a][jd][3] * inv);
            *(bf16x4*)&O[base + jd * 16 + quad * 4] = v;
        }
    }
}

// ---------------------------------------------------------------------------
// Kernel 3: out = O @ Wp^T + b — 128x128, BK=64, single-buffer, fp32 out.
// ---------------------------------------------------------------------------
__global__ __launch_bounds__(256) void gemm_proj_mfma(
    const unsigned short* __restrict__ Ob,
    const unsigned short* __restrict__ Bp,
    const float* __restrict__ bias, float* __restrict__ out)
{
    __shared__ __align__(16) unsigned short As[128 * 64];
    __shared__ __align__(16) unsigned short Bs[128 * 64];

    const int t = threadIdx.x;
    const int w = t >> 6, lane = t & 63;
    const int quad = lane >> 4, l15 = lane & 15;
    const int wm = w >> 1, wn = w & 1;
    const int m0 = blockIdx.y * 128;
    const int n0 = blockIdx.x * 128;
    const int srow = lane >> 3;
    const int sch  = lane & 7;
    const int scw  = (sch ^ srow) * 8;
    const int rb   = l15 & 7;

    floatx4 acc[4][4];
    #pragma unroll
    for (int i = 0; i < 4; ++i)
        #pragma unroll
        for (int j = 0; j < 4; ++j) acc[i][j] = (floatx4){0.f, 0.f, 0.f, 0.f};

    const unsigned short* aG = &Ob[(size_t)(m0 + w * 8 + srow) * EE + scw];
    const unsigned short* bG = &Bp[(size_t)(n0 + w * 8 + srow) * EE + scw];

    for (int kk = 0; kk < EE; kk += 64) {
        #pragma unroll
        for (int p = 0; p < 4; ++p) {
            ASYNC16(aG + kk + (size_t)(p * 32) * EE, &As[(w * 8 + p * 32) * 64]);
            ASYNC16(bG + kk + (size_t)(p * 32) * EE, &Bs[(w * 8 + p * 32) * 64]);
        }
        DRAIN_VMEM();
        __syncthreads();

        #pragma unroll
        for (int s = 0; s < 2; ++s) {
            const int rsw = (((s << 2) | quad) ^ rb) * 8;
            bf16x8 af[4], bf[4];
            #pragma unroll
            for (int i = 0; i < 4; ++i) {
                af[i] = *(const bf16x8*)&As[(wm * 64 + i * 16 + l15) * 64 + rsw];
                bf[i] = *(const bf16x8*)&Bs[(wn * 64 + i * 16 + l15) * 64 + rsw];
            }
            #pragma unroll
            for (int i = 0; i < 4; ++i)
                #pragma unroll
                for (int j = 0; j < 4; ++j)
                    acc[i][j] = __builtin_amdgcn_mfma_f32_16x16x32_bf16(
                        af[i], bf[j], acc[i][j], 0, 0, 0);
        }
        __syncthreads();
    }

    const int mb = m0 + wm * 64;
    const int nb = n0 + wn * 64;
    #pragma unroll
    for (int i = 0; i < 4; ++i) {
        #pragma unroll
        for (int j = 0; j < 4; ++j) {
            float bv = bias[nb + j * 16 + l15];
            #pragma unroll
            for (int r = 0; r < 4; ++r) {
                int mrow = mb + i * 16 + quad * 4 + r;
                out[(size_t)mrow * EE + nb + j * 16 + l15] = acc[i][j][r] + bv;
            }
        }
    }
}

// ---------------------------------------------------------------------------
extern "C" void kernel_launch(void* const* d_in, const int* in_sizes, int n_in,
                              void* d_out, int out_size, void* d_ws, size_t ws_size,
                              hipStream_t stream) {
    const float* x     = (const float*)d_in[0];
    const float* Wqkv  = (const float*)d_in[1];
    const float* bqkv  = (const float*)d_in[2];
    const float* Wproj = (const float*)d_in[3];
    const float* bproj = (const float*)d_in[4];
    float* out = (float*)d_out;

    const size_t BHND = (size_t)BB * HH * NN * DD;      // 16777216
    unsigned short* Q   = (unsigned short*)d_ws;
    unsigned short* K   = Q   + BHND;
    unsigned short* Vn  = K   + BHND;                   // V natural [B,H,N,D]
    unsigned short* Vt  = Vn  + BHND;                   // V^T [B,H,D,N]
    unsigned short* Ob  = Vt  + BHND;                   // [16384][1024] bf16
    unsigned short* xb  = Ob  + BHND;
    unsigned short* Wqt = xb  + BHND;                   // [3072][1024]
    unsigned short* Wpt = Wqt + (size_t)THREE_E * EE;   // [1024][1024]

    dim3 blk(256);
    prep_all<<<dim3(12288), blk, 0, stream>>>(x, xb, Wqkv, Wqt, Wproj, Wpt);

    gemm_qkv_mfma<<<dim3(THREE_E / 128, M_TOTAL / 128), blk, 0, stream>>>(
        xb, Wqt, bqkv, Q, K, Vn);
    vtrans<<<dim3(BB * HH, NN / 64), blk, 0, stream>>>(Vn, Vt);
    attn_mfma<<<dim3(BB * HH * NN / 128), blk, 0, stream>>>(Q, K, Vt, Ob);
    gemm_proj_mfma<<<dim3(EE / 128, M_TOTAL / 128), blk, 0, stream>>>(
        Ob, Wpt, bproj, out);
}

// Round 6
// 394.297 us; speedup vs baseline: 1.0409x; 1.0204x over previous
//
#include <hip/hip_runtime.h>
#include <hip/hip_bf16.h>
#include <math.h>

// Problem constants
#define BB 16
#define NN 1024
#define EE 1024
#define HH 16
#define DD 64
#define THREE_E 3072
#define M_TOTAL (BB * NN)   // 16384

typedef __attribute__((ext_vector_type(8))) short bf16x8;   // 8 bf16 = 4 VGPR
typedef __attribute__((ext_vector_type(4))) short bf16x4;   // 4 bf16 = 2 VGPR
typedef __attribute__((ext_vector_type(4))) float floatx4;  // MFMA C/D

// Q pre-scale: 1/sqrt(64) * log2(e)  (scores land in exp2 domain)
#define SCALE_Q 0.18033688011112042f

static __device__ __forceinline__ unsigned short f2bf(float f) {
    union { float f; unsigned u; } x; x.f = f;
    unsigned r = x.u + 0x7fffu + ((x.u >> 16) & 1u);
    return (unsigned short)(r >> 16);
}

// raw v_exp_f32 — scores are bounded, skip OCML denormal guards
static __device__ __forceinline__ float fast_exp2(float x) {
#if __has_builtin(__builtin_amdgcn_exp2f)
    return __builtin_amdgcn_exp2f(x);
#else
    float r; __asm__("v_exp_f32 %0, %1" : "=v"(r) : "v"(x)); return r;
#endif
}

// pack 2x floatx4 -> bf16x8 via v_cvt_pk_bf16_f32 (RNE)
static __device__ __forceinline__ bf16x8 pack8v(floatx4 a, floatx4 b) {
    union { bf16x8 v; unsigned u[4]; } r;
    __hip_bfloat162 t;
    t = __float22bfloat162_rn(make_float2(a[0], a[1])); r.u[0] = *(unsigned*)&t;
    t = __float22bfloat162_rn(make_float2(a[2], a[3])); r.u[1] = *(unsigned*)&t;
    t = __float22bfloat162_rn(make_float2(b[0], b[1])); r.u[2] = *(unsigned*)&t;
    t = __float22bfloat162_rn(make_float2(b[2], b[3])); r.u[3] = *(unsigned*)&t;
    return r.v;
}
static __device__ __forceinline__ bf16x8 pack8f(float4 a, float4 b) {
    union { bf16x8 v; unsigned u[4]; } r;
    __hip_bfloat162 t;
    t = __float22bfloat162_rn(make_float2(a.x, a.y)); r.u[0] = *(unsigned*)&t;
    t = __float22bfloat162_rn(make_float2(a.z, a.w)); r.u[1] = *(unsigned*)&t;
    t = __float22bfloat162_rn(make_float2(b.x, b.y)); r.u[2] = *(unsigned*)&t;
    t = __float22bfloat162_rn(make_float2(b.z, b.w)); r.u[3] = *(unsigned*)&t;
    return r.v;
}

// async global->LDS, 16B per lane (LDS dest wave-uniform, +lane*16 implicit)
#define ASYNC16(gp, lp)                                                \
    __builtin_amdgcn_global_load_lds(                                  \
        (const __attribute__((address_space(1))) void*)(gp),           \
        (__attribute__((address_space(3))) void*)(lp), 16, 0, 0)

#define DRAIN_VMEM() __asm__ __volatile__("s_waitcnt vmcnt(0)" ::: "memory")

// ---------------------------------------------------------------------------
// Merged prep: convert_x (blocks 0..8191), wtrans Wqkv (8192..11263),
// wtrans Wproj (11264..12287). One dispatch instead of three.
// ---------------------------------------------------------------------------
__global__ __launch_bounds__(256) void prep_all(
    const float* __restrict__ x, unsigned short* __restrict__ xb,
    const float* __restrict__ Wqkv, unsigned short* __restrict__ Wqt,
    const float* __restrict__ Wproj, unsigned short* __restrict__ Wpt)
{
    __shared__ float tile[32][33];
    const int bid = blockIdx.x;
    const int t = threadIdx.x;

    if (bid < 8192) {
        int i = bid * 256 + t;
        const float4* xp = (const float4*)x;
        float4 a = xp[i * 2], b = xp[i * 2 + 1];
        *(bf16x8*)&xb[i * 8] = pack8f(a, b);
        return;
    }

    const float* w; unsigned short* wt; int R, C, bx, by;
    if (bid < 8192 + 3072) {
        int local = bid - 8192;
        bx = local % 96; by = local / 96;
        w = Wqkv; wt = Wqt; R = EE; C = THREE_E;
    } else {
        int local = bid - 11264;
        bx = local % 32; by = local / 32;
        w = Wproj; wt = Wpt; R = EE; C = EE;
    }
    const int lr = t >> 5, lc = t & 31;
    const int r0 = by * 32, c0 = bx * 32;
    #pragma unroll
    for (int p = 0; p < 4; ++p)
        tile[lr + p * 8][lc] = w[(size_t)(r0 + lr + p * 8) * C + c0 + lc];
    __syncthreads();
    #pragma unroll
    for (int p = 0; p < 4; ++p) {
        int oc = lr + p * 8;
        float v = tile[lc][oc];
        wt[(size_t)(c0 + oc) * R + r0 + lc] = f2bf(v);
    }
}

// ---------------------------------------------------------------------------
// Kernel 1: qkv = xb @ Wqkv^T + b (bf16 MFMA).
// R3-proven structure (125.4us): 128x128, BK=64, single-buffer.
// Occupancy-driven implicit overlap beats explicit dbuf here (R1/R4 evidence).
// Swizzle sigma(row)=row&7 over 16B chunks (conflict-free b128 reads).
// ---------------------------------------------------------------------------
__global__ __launch_bounds__(256) void gemm_qkv_mfma(
    const unsigned short* __restrict__ xb,
    const unsigned short* __restrict__ wt,
    const float* __restrict__ bias,
    unsigned short* __restrict__ Qo, unsigned short* __restrict__ Ko,
    unsigned short* __restrict__ Vo)
{
    __shared__ __align__(16) unsigned short As[128 * 64];   // 16 KB
    __shared__ __align__(16) unsigned short Bs[128 * 64];   // 16 KB

    const int t = threadIdx.x;
    const int w = t >> 6, lane = t & 63;
    const int quad = lane >> 4, l15 = lane & 15;
    const int wm = w >> 1, wn = w & 1;
    const int m0 = blockIdx.y * 128;
    const int n0 = blockIdx.x * 128;
    const int srow = lane >> 3;            // 0..7: row within 8-row stripe
    const int sch  = lane & 7;             // 16B chunk slot within 128B row
    const int scw  = (sch ^ srow) * 8;     // swizzled global k-chunk (elems)
    const int rb   = l15 & 7;              // read swizzle base (= row&7)

    floatx4 acc[4][4];
    #pragma unroll
    for (int i = 0; i < 4; ++i)
        #pragma unroll
        for (int j = 0; j < 4; ++j) acc[i][j] = (floatx4){0.f, 0.f, 0.f, 0.f};

    const unsigned short* aG = &xb[(size_t)(m0 + w * 8 + srow) * EE + scw];
    const unsigned short* bG = &wt[(size_t)(n0 + w * 8 + srow) * EE + scw];

    for (int kk = 0; kk < EE; kk += 64) {
        #pragma unroll
        for (int p = 0; p < 4; ++p) {
            ASYNC16(aG + kk + (size_t)(p * 32) * EE, &As[(w * 8 + p * 32) * 64]);
            ASYNC16(bG + kk + (size_t)(p * 32) * EE, &Bs[(w * 8 + p * 32) * 64]);
        }
        DRAIN_VMEM();
        __syncthreads();

        #pragma unroll
        for (int s = 0; s < 2; ++s) {
            const int rsw = (((s << 2) | quad) ^ rb) * 8;
            bf16x8 af[4], bf[4];
            #pragma unroll
            for (int i = 0; i < 4; ++i) {
                af[i] = *(const bf16x8*)&As[(wm * 64 + i * 16 + l15) * 64 + rsw];
                bf[i] = *(const bf16x8*)&Bs[(wn * 64 + i * 16 + l15) * 64 + rsw];
            }
            #pragma unroll
            for (int i = 0; i < 4; ++i)
                #pragma unroll
                for (int j = 0; j < 4; ++j)
                    acc[i][j] = __builtin_amdgcn_mfma_f32_16x16x32_bf16(
                        af[i], bf[j], acc[i][j], 0, 0, 0);
        }
        __syncthreads();
    }

    const int mb = m0 + wm * 64;
    const int nb = n0 + wn * 64;
    #pragma unroll
    for (int i = 0; i < 4; ++i) {
        #pragma unroll
        for (int j = 0; j < 4; ++j) {
            int nc = nb + j * 16;
            int which = nc >> 10;
            int e0 = nc & 1023;
            int h  = e0 >> 6;
            int d0 = e0 & 63;
            float bv = bias[nc + l15];
            #pragma unroll
            for (int r = 0; r < 4; ++r) {
                int m = mb + i * 16 + quad * 4 + r;
                int b = m >> 10, n = m & 1023;
                size_t off = ((size_t)(b * HH + h) * NN + n) * DD + d0 + l15;
                float v = acc[i][j][r] + bv;
                if (which == 0)      Qo[off] = f2bf(v * SCALE_Q);
                else if (which == 1) Ko[off] = f2bf(v);
                else                 Vo[off] = f2bf(v);
            }
        }
    }
}

// ---------------------------------------------------------------------------
// Kernel 2: transposed-score flash attention, bf16 MFMA.
// R6: V staged directly from NATURAL [B,H,N,D] layout — the transpose into
// the swizzled Vs[d][k] layout happens at the LDS scatter-write (16 scalar
// b16 stores/thread, k=srow fixed so block/offset are thread constants).
// This deletes the vtrans kernel + Vt buffer (64 MB HBM round-trip).
// Layout contract (matches pf packing): element (d,k) lives at
//   d*64 + ((B(k) ^ (d&7))<<3) + H(k)*4 + (k&3),
//   B(k)=((k>>2)&3)|((k>>5)<<2), H(k)=(k>>4)&1.
// Double-buffered K/V LDS slots + A/B register sets (R5 structure).
// ---------------------------------------------------------------------------
__global__ __launch_bounds__(256) void attn_mfma(
    const unsigned short* __restrict__ Q,
    const unsigned short* __restrict__ K,
    const unsigned short* __restrict__ Vn,
    unsigned short* __restrict__ O)
{
    __shared__ __align__(16) unsigned short Ks[2][64 * 64];  // [key][d], swizzled
    __shared__ __align__(16) unsigned short Vs[2][64 * 64];  // [d][k], swizzled

    const int t    = threadIdx.x;
    const int w    = t >> 6;
    const int quad = (t >> 4) & 3;
    const int l15  = t & 15;
    const int i    = blockIdx.x;                 // 0..2047
    const int bh   = ((i >> 6) << 3) | (i & 7);  // XCD-local bh windows
    const int qt   = (i >> 3) & 7;

    const unsigned short* Qg = Q  + (size_t)bh * NN * DD;
    const unsigned short* Kg = K  + (size_t)bh * NN * DD;
    const unsigned short* Vg = Vn + (size_t)bh * NN * DD;

    const int q0 = qt * 128 + w * 32;

    bf16x8 qf[2][2];
    #pragma unroll
    for (int a = 0; a < 2; ++a) {
        qf[a][0] = *(const bf16x8*)&Qg[(size_t)(q0 + a * 16 + l15) * DD + quad * 8];
        qf[a][1] = *(const bf16x8*)&Qg[(size_t)(q0 + a * 16 + l15) * DD + 32 + quad * 8];
    }

    // all-ones A-fragment: mfma(ones, P) -> every output element = column sum
    bf16x8 onesA;
    #pragma unroll
    for (int z = 0; z < 8; ++z) onesA[z] = (short)0x3F80;  // bf16 1.0

    floatx4 oa[2][4];
    #pragma unroll
    for (int a = 0; a < 2; ++a)
        #pragma unroll
        for (int jd = 0; jd < 4; ++jd) oa[a][jd] = (floatx4){0.f, 0.f, 0.f, 0.f};
    floatx4 ls[2];
    ls[0] = (floatx4){0.f, 0.f, 0.f, 0.f};
    ls[1] = (floatx4){0.f, 0.f, 0.f, 0.f};

    const int srow = t >> 2;          // k-row 0..63 (for K and V staging)
    const int sc   = t & 3;           // 16-elem slice
    const int swz  = srow & 7;
    const int cbase = ((quad ^ (l15 & 7)) << 3);

    // V-scatter constants: k = srow fixed per thread
    const int Bk = ((srow >> 2) & 3) | (((srow >> 5) & 1) << 2);
    const int c0 = (((srow >> 4) & 1) << 2) | (srow & 3);

    bf16x8 krA0, krA1, vrA0, vrA1;   // reg set A
    bf16x8 krB0, krB1, vrB0, vrB1;   // reg set B

#define LOADKV(T, k0, k1, v0, v1) do {                                      \
    const unsigned short* kg_ = &Kg[(size_t)((T) * 64 + srow) * DD + sc * 16];\
    k0 = *(const bf16x8*)&kg_[0];                                           \
    k1 = *(const bf16x8*)&kg_[8];                                           \
    const unsigned short* vg_ = &Vg[(size_t)((T) * 64 + srow) * DD + sc * 16];\
    v0 = *(const bf16x8*)&vg_[0];                                           \
    v1 = *(const bf16x8*)&vg_[8]; } while (0)

#define WRITEKV(S, k0, k1, v0, v1) do {                                     \
    *(bf16x8*)&Ks[S][srow * 64 + (((2 * sc + 0) ^ swz) << 3)] = k0;         \
    *(bf16x8*)&Ks[S][srow * 64 + (((2 * sc + 1) ^ swz) << 3)] = k1;         \
    _Pragma("unroll")                                                       \
    for (int z = 0; z < 8; ++z) {                                           \
        const int swb = ((Bk ^ z) << 3) + c0;                               \
        const int dB = (sc * 16 + z) * 64;                                  \
        Vs[S][dB + swb]       = v0[z];                                      \
        Vs[S][dB + 512 + swb] = v1[z];                                      \
    } } while (0)

#define COMPUTE(S) do {                                                     \
    floatx4 sa[2][4];                                                       \
    _Pragma("unroll")                                                       \
    for (int a = 0; a < 2; ++a)                                             \
        _Pragma("unroll")                                                   \
        for (int tt = 0; tt < 4; ++tt) sa[a][tt] = (floatx4){0.f,0.f,0.f,0.f};\
    __builtin_amdgcn_s_setprio(1);                                          \
    _Pragma("unroll")                                                       \
    for (int tt = 0; tt < 4; ++tt) {                                        \
        const unsigned short* kb = &Ks[S][(tt * 16 + l15) * 64];            \
        bf16x8 kf0 = *(const bf16x8*)&kb[cbase];                            \
        bf16x8 kf1 = *(const bf16x8*)&kb[cbase ^ 32];                       \
        _Pragma("unroll")                                                   \
        for (int a = 0; a < 2; ++a) {                                       \
            sa[a][tt] = __builtin_amdgcn_mfma_f32_16x16x32_bf16(            \
                kf0, qf[a][0], sa[a][tt], 0, 0, 0);                         \
            sa[a][tt] = __builtin_amdgcn_mfma_f32_16x16x32_bf16(            \
                kf1, qf[a][1], sa[a][tt], 0, 0, 0);                         \
        }                                                                   \
    }                                                                       \
    __builtin_amdgcn_s_setprio(0);                                          \
    bf16x8 pf[2][2];                                                        \
    _Pragma("unroll")                                                       \
    for (int a = 0; a < 2; ++a) {                                           \
        floatx4 pe[4];                                                      \
        _Pragma("unroll")                                                   \
        for (int tt = 0; tt < 4; ++tt) {                                    \
            _Pragma("unroll")                                               \
            for (int r = 0; r < 4; ++r)                                     \
                pe[tt][r] = fast_exp2(sa[a][tt][r]);                        \
        }                                                                   \
        pf[a][0] = pack8v(pe[0], pe[1]);                                    \
        pf[a][1] = pack8v(pe[2], pe[3]);                                    \
    }                                                                       \
    __builtin_amdgcn_s_setprio(1);                                          \
    _Pragma("unroll")                                                       \
    for (int a = 0; a < 2; ++a) {                                           \
        ls[a] = __builtin_amdgcn_mfma_f32_16x16x32_bf16(                    \
            onesA, pf[a][0], ls[a], 0, 0, 0);                               \
        ls[a] = __builtin_amdgcn_mfma_f32_16x16x32_bf16(                    \
            onesA, pf[a][1], ls[a], 0, 0, 0);                               \
    }                                                                       \
    _Pragma("unroll")                                                       \
    for (int jd = 0; jd < 4; ++jd) {                                        \
        const unsigned short* vb = &Vs[S][(jd * 16 + l15) * 64];            \
        bf16x8 vf0 = *(const bf16x8*)&vb[cbase];                            \
        bf16x8 vf1 = *(const bf16x8*)&vb[cbase ^ 32];                       \
        _Pragma("unroll")                                                   \
        for (int a = 0; a < 2; ++a) {                                       \
            oa[a][jd] = __builtin_amdgcn_mfma_f32_16x16x32_bf16(            \
                vf0, pf[a][0], oa[a][jd], 0, 0, 0);                         \
            oa[a][jd] = __builtin_amdgcn_mfma_f32_16x16x32_bf16(            \
                vf1, pf[a][1], oa[a][jd], 0, 0, 0);                         \
        }                                                                   \
    }                                                                       \
    __builtin_amdgcn_s_setprio(0); } while (0)

    // prologue: tile0 -> regs A -> slot0; tile1 -> regs B (in flight)
    LOADKV(0, krA0, krA1, vrA0, vrA1);
    WRITEKV(0, krA0, krA1, vrA0, vrA1);   // compiler waits vmcnt for data regs
    LOADKV(1, krB0, krB1, vrB0, vrB1);
    __syncthreads();                       // slot0 visible; tile1 regs valid

    #pragma unroll 1
    for (int p = 0; p < 8; ++p) {
        // even tile e = 2p: compute slot0; write tile e+1 (B) -> slot1
        WRITEKV(1, krB0, krB1, vrB0, vrB1);
        if (p < 7) LOADKV(2 * p + 2, krA0, krA1, vrA0, vrA1);
        COMPUTE(0);
        __syncthreads();                   // slot1 visible; A-regs valid
        // odd tile o = 2p+1: compute slot1; write tile o+1 (A) -> slot0
        if (p < 7) {
            WRITEKV(0, krA0, krA1, vrA0, vrA1);
            LOADKV(2 * p + 3, krB0, krB1, vrB0, vrB1);
        }
        COMPUTE(1);
        __syncthreads();                   // slot0 visible; B-regs valid
    }
#undef LOADKV
#undef WRITEKV
#undef COMPUTE

    const int b = bh >> 4, h = bh & 15;
    #pragma unroll
    for (int a = 0; a < 2; ++a) {
        float inv = 1.f / ls[a][0];   // every row of ls holds the full sum
        int n = q0 + a * 16 + l15;
        size_t base = (size_t)(b * NN + n) * EE + h * DD;
        #pragma unroll
        for (int jd = 0; jd < 4; ++jd) {
            bf16x4 v;
            v[0] = (short)f2bf(oa[a][jd][0] * inv);
            v[1] = (short)f2bf(oa[a][jd][1] * inv);
            v[2] = (short)f2bf(oa[a][jd][2] * inv);
            v[3] = (short)f2bf(oa[a][jd][3] * inv);
            *(bf16x4*)&O[base + jd * 16 + quad * 4] = v;
        }
    }
}

// ---------------------------------------------------------------------------
// Kernel 3: out = O @ Wp^T + b — 128x128, BK=64, single-buffer, fp32 out.
// ---------------------------------------------------------------------------
__global__ __launch_bounds__(256) void gemm_proj_mfma(
    const unsigned short* __restrict__ Ob,
    const unsigned short* __restrict__ Bp,
    const float* __restrict__ bias, float* __restrict__ out)
{
    __shared__ __align__(16) unsigned short As[128 * 64];
    __shared__ __align__(16) unsigned short Bs[128 * 64];

    const int t = threadIdx.x;
    const int w = t >> 6, lane = t & 63;
    const int quad = lane >> 4, l15 = lane & 15;
    const int wm = w >> 1, wn = w & 1;
    const int m0 = blockIdx.y * 128;
    const int n0 = blockIdx.x * 128;
    const int srow = lane >> 3;
    const int sch  = lane & 7;
    const int scw  = (sch ^ srow) * 8;
    const int rb   = l15 & 7;

    floatx4 acc[4][4];
    #pragma unroll
    for (int i = 0; i < 4; ++i)
        #pragma unroll
        for (int j = 0; j < 4; ++j) acc[i][j] = (floatx4){0.f, 0.f, 0.f, 0.f};

    const unsigned short* aG = &Ob[(size_t)(m0 + w * 8 + srow) * EE + scw];
    const unsigned short* bG = &Bp[(size_t)(n0 + w * 8 + srow) * EE + scw];

    for (int kk = 0; kk < EE; kk += 64) {
        #pragma unroll
        for (int p = 0; p < 4; ++p) {
            ASYNC16(aG + kk + (size_t)(p * 32) * EE, &As[(w * 8 + p * 32) * 64]);
            ASYNC16(bG + kk + (size_t)(p * 32) * EE, &Bs[(w * 8 + p * 32) * 64]);
        }
        DRAIN_VMEM();
        __syncthreads();

        #pragma unroll
        for (int s = 0; s < 2; ++s) {
            const int rsw = (((s << 2) | quad) ^ rb) * 8;
            bf16x8 af[4], bf[4];
            #pragma unroll
            for (int i = 0; i < 4; ++i) {
                af[i] = *(const bf16x8*)&As[(wm * 64 + i * 16 + l15) * 64 + rsw];
                bf[i] = *(const bf16x8*)&Bs[(wn * 64 + i * 16 + l15) * 64 + rsw];
            }
            #pragma unroll
            for (int i = 0; i < 4; ++i)
                #pragma unroll
                for (int j = 0; j < 4; ++j)
                    acc[i][j] = __builtin_amdgcn_mfma_f32_16x16x32_bf16(
                        af[i], bf[j], acc[i][j], 0, 0, 0);
        }
        __syncthreads();
    }

    const int mb = m0 + wm * 64;
    const int nb = n0 + wn * 64;
    #pragma unroll
    for (int i = 0; i < 4; ++i) {
        #pragma unroll
        for (int j = 0; j < 4; ++j) {
            float bv = bias[nb + j * 16 + l15];
            #pragma unroll
            for (int r = 0; r < 4; ++r) {
                int mrow = mb + i * 16 + quad * 4 + r;
                out[(size_t)mrow * EE + nb + j * 16 + l15] = acc[i][j][r] + bv;
            }
        }
    }
}

// ---------------------------------------------------------------------------
extern "C" void kernel_launch(void* const* d_in, const int* in_sizes, int n_in,
                              void* d_out, int out_size, void* d_ws, size_t ws_size,
                              hipStream_t stream) {
    const float* x     = (const float*)d_in[0];
    const float* Wqkv  = (const float*)d_in[1];
    const float* bqkv  = (const float*)d_in[2];
    const float* Wproj = (const float*)d_in[3];
    const float* bproj = (const float*)d_in[4];
    float* out = (float*)d_out;

    const size_t BHND = (size_t)BB * HH * NN * DD;      // 16777216
    unsigned short* Q   = (unsigned short*)d_ws;
    unsigned short* K   = Q   + BHND;
    unsigned short* Vn  = K   + BHND;                   // V natural [B,H,N,D]
    unsigned short* Ob  = Vn  + BHND;                   // [16384][1024] bf16
    unsigned short* xb  = Ob  + BHND;
    unsigned short* Wqt = xb  + BHND;                   // [3072][1024]
    unsigned short* Wpt = Wqt + (size_t)THREE_E * EE;   // [1024][1024]

    dim3 blk(256);
    prep_all<<<dim3(12288), blk, 0, stream>>>(x, xb, Wqkv, Wqt, Wproj, Wpt);

    gemm_qkv_mfma<<<dim3(THREE_E / 128, M_TOTAL / 128), blk, 0, stream>>>(
        xb, Wqt, bqkv, Q, K, Vn);
    attn_mfma<<<dim3(BB * HH * NN / 128), blk, 0, stream>>>(Q, K, Vn, Ob);
    gemm_proj_mfma<<<dim3(EE / 128, M_TOTAL / 128), blk, 0, stream>>>(
        Ob, Wpt, bproj, out);
}

// Round 7
// 374.772 us; speedup vs baseline: 1.0952x; 1.0521x over previous
//
#include <hip/hip_runtime.h>
#include <hip/hip_bf16.h>
#include <math.h>

// Problem constants
#define BB 16
#define NN 1024
#define EE 1024
#define HH 16
#define DD 64
#define THREE_E 3072
#define M_TOTAL (BB * NN)   // 16384

typedef __attribute__((ext_vector_type(8))) short bf16x8;   // 8 bf16 = 4 VGPR
typedef __attribute__((ext_vector_type(4))) short bf16x4;   // 4 bf16 = 2 VGPR
typedef __attribute__((ext_vector_type(4))) float floatx4;  // MFMA C/D

// Q pre-scale: 1/sqrt(64) * log2(e)  (scores land in exp2 domain)
#define SCALE_Q 0.18033688011112042f

static __device__ __forceinline__ unsigned short f2bf(float f) {
    union { float f; unsigned u; } x; x.f = f;
    unsigned r = x.u + 0x7fffu + ((x.u >> 16) & 1u);
    return (unsigned short)(r >> 16);
}

// raw v_exp_f32 — scores are bounded, skip OCML denormal guards
static __device__ __forceinline__ float fast_exp2(float x) {
#if __has_builtin(__builtin_amdgcn_exp2f)
    return __builtin_amdgcn_exp2f(x);
#else
    float r; __asm__("v_exp_f32 %0, %1" : "=v"(r) : "v"(x)); return r;
#endif
}

// pack 2x floatx4 -> bf16x8 via v_cvt_pk_bf16_f32 (RNE)
static __device__ __forceinline__ bf16x8 pack8v(floatx4 a, floatx4 b) {
    union { bf16x8 v; unsigned u[4]; } r;
    __hip_bfloat162 t;
    t = __float22bfloat162_rn(make_float2(a[0], a[1])); r.u[0] = *(unsigned*)&t;
    t = __float22bfloat162_rn(make_float2(a[2], a[3])); r.u[1] = *(unsigned*)&t;
    t = __float22bfloat162_rn(make_float2(b[0], b[1])); r.u[2] = *(unsigned*)&t;
    t = __float22bfloat162_rn(make_float2(b[2], b[3])); r.u[3] = *(unsigned*)&t;
    return r.v;
}
static __device__ __forceinline__ bf16x8 pack8f(float4 a, float4 b) {
    union { bf16x8 v; unsigned u[4]; } r;
    __hip_bfloat162 t;
    t = __float22bfloat162_rn(make_float2(a.x, a.y)); r.u[0] = *(unsigned*)&t;
    t = __float22bfloat162_rn(make_float2(a.z, a.w)); r.u[1] = *(unsigned*)&t;
    t = __float22bfloat162_rn(make_float2(b.x, b.y)); r.u[2] = *(unsigned*)&t;
    t = __float22bfloat162_rn(make_float2(b.z, b.w)); r.u[3] = *(unsigned*)&t;
    return r.v;
}

// async global->LDS, 16B per lane (LDS dest wave-uniform, +lane*16 implicit)
#define ASYNC16(gp, lp)                                                \
    __builtin_amdgcn_global_load_lds(                                  \
        (const __attribute__((address_space(1))) void*)(gp),           \
        (__attribute__((address_space(3))) void*)(lp), 16, 0, 0)

#define DRAIN_VMEM() __asm__ __volatile__("s_waitcnt vmcnt(0)" ::: "memory")

// ---------------------------------------------------------------------------
// Merged prep: convert_x (blocks 0..8191), wtrans Wqkv (8192..11263),
// wtrans Wproj (11264..12287). One dispatch instead of three.
// ---------------------------------------------------------------------------
__global__ __launch_bounds__(256) void prep_all(
    const float* __restrict__ x, unsigned short* __restrict__ xb,
    const float* __restrict__ Wqkv, unsigned short* __restrict__ Wqt,
    const float* __restrict__ Wproj, unsigned short* __restrict__ Wpt)
{
    __shared__ float tile[32][33];
    const int bid = blockIdx.x;
    const int t = threadIdx.x;

    if (bid < 8192) {
        int i = bid * 256 + t;
        const float4* xp = (const float4*)x;
        float4 a = xp[i * 2], b = xp[i * 2 + 1];
        *(bf16x8*)&xb[i * 8] = pack8f(a, b);
        return;
    }

    const float* w; unsigned short* wt; int R, C, bx, by;
    if (bid < 8192 + 3072) {
        int local = bid - 8192;
        bx = local % 96; by = local / 96;
        w = Wqkv; wt = Wqt; R = EE; C = THREE_E;
    } else {
        int local = bid - 11264;
        bx = local % 32; by = local / 32;
        w = Wproj; wt = Wpt; R = EE; C = EE;
    }
    const int lr = t >> 5, lc = t & 31;
    const int r0 = by * 32, c0 = bx * 32;
    #pragma unroll
    for (int p = 0; p < 4; ++p)
        tile[lr + p * 8][lc] = w[(size_t)(r0 + lr + p * 8) * C + c0 + lc];
    __syncthreads();
    #pragma unroll
    for (int p = 0; p < 4; ++p) {
        int oc = lr + p * 8;
        float v = tile[lc][oc];
        wt[(size_t)(c0 + oc) * R + r0 + lc] = f2bf(v);
    }
}

// ---------------------------------------------------------------------------
// Kernel 1: qkv = xb @ Wqkv^T + b (bf16 MFMA).
// R7: 256x128 block tile (2x2 waves, 128x64 per-wave tile, acc[8][4]).
// Rationale: LDS-BW-bound — frag reads scale with (Mw+Nw)*K, FLOPs with
// Mw*Nw*K. 128x64 wave tile = 0.375 b128-reads/MFMA (was 0.5), staging
// bytes/FLOP -27%, 64 MFMA per wave per K-step (2x per drain event).
// Single-buffer BK=64 skeleton, swizzle, global_load_lds all unchanged (R3).
// ---------------------------------------------------------------------------
__global__ __launch_bounds__(256, 2) void gemm_qkv_mfma(
    const unsigned short* __restrict__ xb,
    const unsigned short* __restrict__ wt,
    const float* __restrict__ bias,
    unsigned short* __restrict__ Qo, unsigned short* __restrict__ Ko,
    unsigned short* __restrict__ Vo)
{
    __shared__ __align__(16) unsigned short As[256 * 64];   // 32 KB
    __shared__ __align__(16) unsigned short Bs[128 * 64];   // 16 KB

    const int t = threadIdx.x;
    const int w = t >> 6, lane = t & 63;
    const int quad = lane >> 4, l15 = lane & 15;
    const int wm = w >> 1, wn = w & 1;       // 2x2 wave grid
    const int m0 = blockIdx.y * 256;
    const int n0 = blockIdx.x * 128;
    const int srow = lane >> 3;            // 0..7: row within 8-row stripe
    const int sch  = lane & 7;             // 16B chunk slot within 128B row
    const int scw  = (sch ^ srow) * 8;     // swizzled global k-chunk (elems)
    const int rb   = l15 & 7;              // read swizzle base (= row&7)

    floatx4 acc[8][4];
    #pragma unroll
    for (int i = 0; i < 8; ++i)
        #pragma unroll
        for (int j = 0; j < 4; ++j) acc[i][j] = (floatx4){0.f, 0.f, 0.f, 0.f};

    const unsigned short* aG = &xb[(size_t)(m0 + w * 8 + srow) * EE + scw];
    const unsigned short* bG = &wt[(size_t)(n0 + w * 8 + srow) * EE + scw];

    for (int kk = 0; kk < EE; kk += 64) {
        #pragma unroll
        for (int p = 0; p < 8; ++p)
            ASYNC16(aG + kk + (size_t)(p * 32) * EE, &As[(w * 8 + p * 32) * 64]);
        #pragma unroll
        for (int p = 0; p < 4; ++p)
            ASYNC16(bG + kk + (size_t)(p * 32) * EE, &Bs[(w * 8 + p * 32) * 64]);
        DRAIN_VMEM();
        __syncthreads();

        #pragma unroll
        for (int s = 0; s < 2; ++s) {
            const int rsw = (((s << 2) | quad) ^ rb) * 8;
            bf16x8 af[8], bf[4];
            #pragma unroll
            for (int j = 0; j < 4; ++j)
                bf[j] = *(const bf16x8*)&Bs[(wn * 64 + j * 16 + l15) * 64 + rsw];
            #pragma unroll
            for (int i = 0; i < 8; ++i)
                af[i] = *(const bf16x8*)&As[(wm * 128 + i * 16 + l15) * 64 + rsw];
            __builtin_amdgcn_s_setprio(1);
            #pragma unroll
            for (int i = 0; i < 8; ++i)
                #pragma unroll
                for (int j = 0; j < 4; ++j)
                    acc[i][j] = __builtin_amdgcn_mfma_f32_16x16x32_bf16(
                        af[i], bf[j], acc[i][j], 0, 0, 0);
            __builtin_amdgcn_s_setprio(0);
        }
        __syncthreads();
    }

    const int mb = m0 + wm * 128;
    const int nb = n0 + wn * 64;
    #pragma unroll
    for (int i = 0; i < 8; ++i) {
        #pragma unroll
        for (int j = 0; j < 4; ++j) {
            int nc = nb + j * 16;
            int which = nc >> 10;
            int e0 = nc & 1023;
            int h  = e0 >> 6;
            int d0 = e0 & 63;
            float bv = bias[nc + l15];
            #pragma unroll
            for (int r = 0; r < 4; ++r) {
                int m = mb + i * 16 + quad * 4 + r;
                int b = m >> 10, n = m & 1023;
                size_t off = ((size_t)(b * HH + h) * NN + n) * DD + d0 + l15;
                float v = acc[i][j][r] + bv;
                if (which == 0)      Qo[off] = f2bf(v * SCALE_Q);
                else if (which == 1) Ko[off] = f2bf(v);
                else                 Vo[off] = f2bf(v);
            }
        }
    }
}

// ---------------------------------------------------------------------------
// Kernel 2: transposed-score flash attention, bf16 MFMA (unchanged from R6:
// fused V-transpose at LDS write, dbuf slots, exp2, MFMA-ones row-sum).
// ---------------------------------------------------------------------------
__global__ __launch_bounds__(256) void attn_mfma(
    const unsigned short* __restrict__ Q,
    const unsigned short* __restrict__ K,
    const unsigned short* __restrict__ Vn,
    unsigned short* __restrict__ O)
{
    __shared__ __align__(16) unsigned short Ks[2][64 * 64];  // [key][d], swizzled
    __shared__ __align__(16) unsigned short Vs[2][64 * 64];  // [d][k], swizzled

    const int t    = threadIdx.x;
    const int w    = t >> 6;
    const int quad = (t >> 4) & 3;
    const int l15  = t & 15;
    const int i    = blockIdx.x;                 // 0..2047
    const int bh   = ((i >> 6) << 3) | (i & 7);  // XCD-local bh windows
    const int qt   = (i >> 3) & 7;

    const unsigned short* Qg = Q  + (size_t)bh * NN * DD;
    const unsigned short* Kg = K  + (size_t)bh * NN * DD;
    const unsigned short* Vg = Vn + (size_t)bh * NN * DD;

    const int q0 = qt * 128 + w * 32;

    bf16x8 qf[2][2];
    #pragma unroll
    for (int a = 0; a < 2; ++a) {
        qf[a][0] = *(const bf16x8*)&Qg[(size_t)(q0 + a * 16 + l15) * DD + quad * 8];
        qf[a][1] = *(const bf16x8*)&Qg[(size_t)(q0 + a * 16 + l15) * DD + 32 + quad * 8];
    }

    // all-ones A-fragment: mfma(ones, P) -> every output element = column sum
    bf16x8 onesA;
    #pragma unroll
    for (int z = 0; z < 8; ++z) onesA[z] = (short)0x3F80;  // bf16 1.0

    floatx4 oa[2][4];
    #pragma unroll
    for (int a = 0; a < 2; ++a)
        #pragma unroll
        for (int jd = 0; jd < 4; ++jd) oa[a][jd] = (floatx4){0.f, 0.f, 0.f, 0.f};
    floatx4 ls[2];
    ls[0] = (floatx4){0.f, 0.f, 0.f, 0.f};
    ls[1] = (floatx4){0.f, 0.f, 0.f, 0.f};

    const int srow = t >> 2;          // k-row 0..63 (for K and V staging)
    const int sc   = t & 3;           // 16-elem slice
    const int swz  = srow & 7;
    const int cbase = ((quad ^ (l15 & 7)) << 3);

    // V-scatter constants: k = srow fixed per thread
    const int Bk = ((srow >> 2) & 3) | (((srow >> 5) & 1) << 2);
    const int c0 = (((srow >> 4) & 1) << 2) | (srow & 3);

    bf16x8 krA0, krA1, vrA0, vrA1;   // reg set A
    bf16x8 krB0, krB1, vrB0, vrB1;   // reg set B

#define LOADKV(T, k0, k1, v0, v1) do {                                      \
    const unsigned short* kg_ = &Kg[(size_t)((T) * 64 + srow) * DD + sc * 16];\
    k0 = *(const bf16x8*)&kg_[0];                                           \
    k1 = *(const bf16x8*)&kg_[8];                                           \
    const unsigned short* vg_ = &Vg[(size_t)((T) * 64 + srow) * DD + sc * 16];\
    v0 = *(const bf16x8*)&vg_[0];                                           \
    v1 = *(const bf16x8*)&vg_[8]; } while (0)

#define WRITEKV(S, k0, k1, v0, v1) do {                                     \
    *(bf16x8*)&Ks[S][srow * 64 + (((2 * sc + 0) ^ swz) << 3)] = k0;         \
    *(bf16x8*)&Ks[S][srow * 64 + (((2 * sc + 1) ^ swz) << 3)] = k1;         \
    _Pragma("unroll")                                                       \
    for (int z = 0; z < 8; ++z) {                                           \
        const int swb = ((Bk ^ z) << 3) + c0;                               \
        const int dB = (sc * 16 + z) * 64;                                  \
        Vs[S][dB + swb]       = v0[z];                                      \
        Vs[S][dB + 512 + swb] = v1[z];                                      \
    } } while (0)

#define COMPUTE(S) do {                                                     \
    floatx4 sa[2][4];                                                       \
    _Pragma("unroll")                                                       \
    for (int a = 0; a < 2; ++a)                                             \
        _Pragma("unroll")                                                   \
        for (int tt = 0; tt < 4; ++tt) sa[a][tt] = (floatx4){0.f,0.f,0.f,0.f};\
    __builtin_amdgcn_s_setprio(1);                                          \
    _Pragma("unroll")                                                       \
    for (int tt = 0; tt < 4; ++tt) {                                        \
        const unsigned short* kb = &Ks[S][(tt * 16 + l15) * 64];            \
        bf16x8 kf0 = *(const bf16x8*)&kb[cbase];                            \
        bf16x8 kf1 = *(const bf16x8*)&kb[cbase ^ 32];                       \
        _Pragma("unroll")                                                   \
        for (int a = 0; a < 2; ++a) {                                       \
            sa[a][tt] = __builtin_amdgcn_mfma_f32_16x16x32_bf16(            \
                kf0, qf[a][0], sa[a][tt], 0, 0, 0);                         \
            sa[a][tt] = __builtin_amdgcn_mfma_f32_16x16x32_bf16(            \
                kf1, qf[a][1], sa[a][tt], 0, 0, 0);                         \
        }                                                                   \
    }                                                                       \
    __builtin_amdgcn_s_setprio(0);                                          \
    bf16x8 pf[2][2];                                                        \
    _Pragma("unroll")                                                       \
    for (int a = 0; a < 2; ++a) {                                           \
        floatx4 pe[4];                                                      \
        _Pragma("unroll")                                                   \
        for (int tt = 0; tt < 4; ++tt) {                                    \
            _Pragma("unroll")                                               \
            for (int r = 0; r < 4; ++r)                                     \
                pe[tt][r] = fast_exp2(sa[a][tt][r]);                        \
        }                                                                   \
        pf[a][0] = pack8v(pe[0], pe[1]);                                    \
        pf[a][1] = pack8v(pe[2], pe[3]);                                    \
    }                                                                       \
    __builtin_amdgcn_s_setprio(1);                                          \
    _Pragma("unroll")                                                       \
    for (int a = 0; a < 2; ++a) {                                           \
        ls[a] = __builtin_amdgcn_mfma_f32_16x16x32_bf16(                    \
            onesA, pf[a][0], ls[a], 0, 0, 0);                               \
        ls[a] = __builtin_amdgcn_mfma_f32_16x16x32_bf16(                    \
            onesA, pf[a][1], ls[a], 0, 0, 0);                               \
    }                                                                       \
    _Pragma("unroll")                                                       \
    for (int jd = 0; jd < 4; ++jd) {                                        \
        const unsigned short* vb = &Vs[S][(jd * 16 + l15) * 64];            \
        bf16x8 vf0 = *(const bf16x8*)&vb[cbase];                            \
        bf16x8 vf1 = *(const bf16x8*)&vb[cbase ^ 32];                       \
        _Pragma("unroll")                                                   \
        for (int a = 0; a < 2; ++a) {                                       \
            oa[a][jd] = __builtin_amdgcn_mfma_f32_16x16x32_bf16(            \
                vf0, pf[a][0], oa[a][jd], 0, 0, 0);                         \
            oa[a][jd] = __builtin_amdgcn_mfma_f32_16x16x32_bf16(            \
                vf1, pf[a][1], oa[a][jd], 0, 0, 0);                         \
        }                                                                   \
    }                                                                       \
    __builtin_amdgcn_s_setprio(0); } while (0)

    // prologue: tile0 -> regs A -> slot0; tile1 -> regs B (in flight)
    LOADKV(0, krA0, krA1, vrA0, vrA1);
    WRITEKV(0, krA0, krA1, vrA0, vrA1);   // compiler waits vmcnt for data regs
    LOADKV(1, krB0, krB1, vrB0, vrB1);
    __syncthreads();                       // slot0 visible; tile1 regs valid

    #pragma unroll 1
    for (int p = 0; p < 8; ++p) {
        // even tile e = 2p: compute slot0; write tile e+1 (B) -> slot1
        WRITEKV(1, krB0, krB1, vrB0, vrB1);
        if (p < 7) LOADKV(2 * p + 2, krA0, krA1, vrA0, vrA1);
        COMPUTE(0);
        __syncthreads();                   // slot1 visible; A-regs valid
        // odd tile o = 2p+1: compute slot1; write tile o+1 (A) -> slot0
        if (p < 7) {
            WRITEKV(0, krA0, krA1, vrA0, vrA1);
            LOADKV(2 * p + 3, krB0, krB1, vrB0, vrB1);
        }
        COMPUTE(1);
        __syncthreads();                   // slot0 visible; B-regs valid
    }
#undef LOADKV
#undef WRITEKV
#undef COMPUTE

    const int b = bh >> 4, h = bh & 15;
    #pragma unroll
    for (int a = 0; a < 2; ++a) {
        float inv = 1.f / ls[a][0];   // every row of ls holds the full sum
        int n = q0 + a * 16 + l15;
        size_t base = (size_t)(b * NN + n) * EE + h * DD;
        #pragma unroll
        for (int jd = 0; jd < 4; ++jd) {
            bf16x4 v;
            v[0] = (short)f2bf(oa[a][jd][0] * inv);
            v[1] = (short)f2bf(oa[a][jd][1] * inv);
            v[2] = (short)f2bf(oa[a][jd][2] * inv);
            v[3] = (short)f2bf(oa[a][jd][3] * inv);
            *(bf16x4*)&O[base + jd * 16 + quad * 4] = v;
        }
    }
}

// ---------------------------------------------------------------------------
// Kernel 3: out = O @ Wp^T + b — 256x128 tile (R7 structure), fp32 out.
// ---------------------------------------------------------------------------
__global__ __launch_bounds__(256, 2) void gemm_proj_mfma(
    const unsigned short* __restrict__ Ob,
    const unsigned short* __restrict__ Bp,
    const float* __restrict__ bias, float* __restrict__ out)
{
    __shared__ __align__(16) unsigned short As[256 * 64];
    __shared__ __align__(16) unsigned short Bs[128 * 64];

    const int t = threadIdx.x;
    const int w = t >> 6, lane = t & 63;
    const int quad = lane >> 4, l15 = lane & 15;
    const int wm = w >> 1, wn = w & 1;
    const int m0 = blockIdx.y * 256;
    const int n0 = blockIdx.x * 128;
    const int srow = lane >> 3;
    const int sch  = lane & 7;
    const int scw  = (sch ^ srow) * 8;
    const int rb   = l15 & 7;

    floatx4 acc[8][4];
    #pragma unroll
    for (int i = 0; i < 8; ++i)
        #pragma unroll
        for (int j = 0; j < 4; ++j) acc[i][j] = (floatx4){0.f, 0.f, 0.f, 0.f};

    const unsigned short* aG = &Ob[(size_t)(m0 + w * 8 + srow) * EE + scw];
    const unsigned short* bG = &Bp[(size_t)(n0 + w * 8 + srow) * EE + scw];

    for (int kk = 0; kk < EE; kk += 64) {
        #pragma unroll
        for (int p = 0; p < 8; ++p)
            ASYNC16(aG + kk + (size_t)(p * 32) * EE, &As[(w * 8 + p * 32) * 64]);
        #pragma unroll
        for (int p = 0; p < 4; ++p)
            ASYNC16(bG + kk + (size_t)(p * 32) * EE, &Bs[(w * 8 + p * 32) * 64]);
        DRAIN_VMEM();
        __syncthreads();

        #pragma unroll
        for (int s = 0; s < 2; ++s) {
            const int rsw = (((s << 2) | quad) ^ rb) * 8;
            bf16x8 af[8], bf[4];
            #pragma unroll
            for (int j = 0; j < 4; ++j)
                bf[j] = *(const bf16x8*)&Bs[(wn * 64 + j * 16 + l15) * 64 + rsw];
            #pragma unroll
            for (int i = 0; i < 8; ++i)
                af[i] = *(const bf16x8*)&As[(wm * 128 + i * 16 + l15) * 64 + rsw];
            __builtin_amdgcn_s_setprio(1);
            #pragma unroll
            for (int i = 0; i < 8; ++i)
                #pragma unroll
                for (int j = 0; j < 4; ++j)
                    acc[i][j] = __builtin_amdgcn_mfma_f32_16x16x32_bf16(
                        af[i], bf[j], acc[i][j], 0, 0, 0);
            __builtin_amdgcn_s_setprio(0);
        }
        __syncthreads();
    }

    const int mb = m0 + wm * 128;
    const int nb = n0 + wn * 64;
    #pragma unroll
    for (int i = 0; i < 8; ++i) {
        #pragma unroll
        for (int j = 0; j < 4; ++j) {
            float bv = bias[nb + j * 16 + l15];
            #pragma unroll
            for (int r = 0; r < 4; ++r) {
                int mrow = mb + i * 16 + quad * 4 + r;
                out[(size_t)mrow * EE + nb + j * 16 + l15] = acc[i][j][r] + bv;
            }
        }
    }
}

// ---------------------------------------------------------------------------
extern "C" void kernel_launch(void* const* d_in, const int* in_sizes, int n_in,
                              void* d_out, int out_size, void* d_ws, size_t ws_size,
                              hipStream_t stream) {
    const float* x     = (const float*)d_in[0];
    const float* Wqkv  = (const float*)d_in[1];
    const float* bqkv  = (const float*)d_in[2];
    const float* Wproj = (const float*)d_in[3];
    const float* bproj = (const float*)d_in[4];
    float* out = (float*)d_out;

    const size_t BHND = (size_t)BB * HH * NN * DD;      // 16777216
    unsigned short* Q   = (unsigned short*)d_ws;
    unsigned short* K   = Q   + BHND;
    unsigned short* Vn  = K   + BHND;                   // V natural [B,H,N,D]
    unsigned short* Ob  = Vn  + BHND;                   // [16384][1024] bf16
    unsigned short* xb  = Ob  + BHND;
    unsigned short* Wqt = xb  + BHND;                   // [3072][1024]
    unsigned short* Wpt = Wqt + (size_t)THREE_E * EE;   // [1024][1024]

    dim3 blk(256);
    prep_all<<<dim3(12288), blk, 0, stream>>>(x, xb, Wqkv, Wqt, Wproj, Wpt);

    gemm_qkv_mfma<<<dim3(THREE_E / 128, M_TOTAL / 256), blk, 0, stream>>>(
        xb, Wqt, bqkv, Q, K, Vn);
    attn_mfma<<<dim3(BB * HH * NN / 128), blk, 0, stream>>>(Q, K, Vn, Ob);
    gemm_proj_mfma<<<dim3(EE / 128, M_TOTAL / 256), blk, 0, stream>>>(
        Ob, Wpt, bproj, out);
}